// Round 1
// baseline (328.433 us; speedup 1.0000x reference)
//
#include <hip/hip_runtime.h>

typedef _Float16 f16;
typedef _Float16 half8 __attribute__((ext_vector_type(8)));
typedef _Float16 half4 __attribute__((ext_vector_type(4)));
typedef float f32x4 __attribute__((ext_vector_type(4)));

#define B_SZ 512
#define NQ   128
#define CH   512
#define NH   8
#define DH   64
#define MTOK (B_SZ*NQ)   // 65536 tokens
#define KD   512

#define MFMA16(a,b,c) __builtin_amdgcn_mfma_f32_16x16x32_f16((a),(b),(c),0,0,0)

// global -> LDS direct DMA, 16B per lane. LDS dest is wave-uniform base + lane*16.
#define GLDS16(g,l) __builtin_amdgcn_global_load_lds( \
    (__attribute__((address_space(1))) void*)(g), \
    (__attribute__((address_space(3))) void*)(l), 16, 0, 0)

// ---------------- kernel 0a: x fp32 -> fp16 ----------------
__global__ __launch_bounds__(256) void k_cvt(const float* __restrict__ x,
                                             f16* __restrict__ xb) {
  const int n8 = MTOK * KD / 8;
  int i = blockIdx.x * blockDim.x + threadIdx.x;
  const int stride = gridDim.x * blockDim.x;
  for (; i < n8; i += stride) {
    f32x4 a = ((const f32x4*)x)[2 * i];
    f32x4 b = ((const f32x4*)x)[2 * i + 1];
    half8 h;
    h[0] = (f16)a[0]; h[1] = (f16)a[1]; h[2] = (f16)a[2]; h[3] = (f16)a[3];
    h[4] = (f16)b[0]; h[5] = (f16)b[1]; h[6] = (f16)b[2]; h[7] = (f16)b[3];
    ((half8*)xb)[i] = h;
  }
}

// ---------------- kernel 0b: W^T fp32 -> fp16 (B^T layout) ----------------
// wt rows 0..511 = Wq cols, 512..1023 = Wk cols, 1024..1535 = Wv cols, 1536..2047 = Wo cols
__global__ __launch_bounds__(256) void k_wt(const float* __restrict__ Wq,
                                            const float* __restrict__ Wk,
                                            const float* __restrict__ Wv,
                                            const float* __restrict__ Wo,
                                            f16* __restrict__ wt) {
  const int n = blockIdx.x;
  const float* W = (n < 512) ? Wq : (n < 1024) ? Wk : (n < 1536) ? Wv : Wo;
  const int c = n & 511;
  for (int k = threadIdx.x; k < 512; k += blockDim.x)
    wt[n * 512 + k] = (f16)W[k * 512 + c];
}

// ---------------- kernel 1: fused QKV projection GEMM ----------------
// C[m][n] = sum_k A[m][k] * Bw[n][k];  M=65536, N=1536, K=512
// epilogue: +bias, scatter Q,K as [b][h][n][d], V transposed as [b][h][d][n]
__global__ __launch_bounds__(256, 2) void k_qkv(
    f16* __restrict__ A, f16* __restrict__ Bw,
    const float* __restrict__ bq, const float* __restrict__ bk,
    const float* __restrict__ bv,
    f16* __restrict__ qb, f16* __restrict__ kb, f16* __restrict__ vb) {
  __shared__ f16 la[128 * 32];
  __shared__ f16 lb[128 * 32];
  const int tid = threadIdx.x;
  const int w = tid >> 6, lane = tid & 63;
  const int ln = lane & 15, g = lane >> 4;
  const int wr = w >> 1, wc = w & 1;
  const int mtile = blockIdx.y, ntile = blockIdx.x;

  // staging geometry: LDS element offset for this wave's issue-0 = w*512 + lane*8
  const int e0 = w * 512 + lane * 8;
  const int srow = e0 >> 5, scol = e0 & 31;
  f16* gA = A + (mtile * 128 + srow) * KD + scol;
  f16* gB = Bw + (ntile * 128 + srow) * KD + scol;
  f16* lA = la + w * 512;
  f16* lB = lb + w * 512;

  f32x4 acc[4][4] = {};

  for (int kt = 0; kt < 16; ++kt) {
    const int k0 = kt * 32;
    GLDS16(gA + k0, lA);
    GLDS16(gA + 64 * KD + k0, lA + 2048);
    GLDS16(gB + k0, lB);
    GLDS16(gB + 64 * KD + k0, lB + 2048);
    __syncthreads();   // compiler drains vmcnt before s_barrier
    half8 af[4], bf[4];
#pragma unroll
    for (int m = 0; m < 4; ++m)
      af[m] = *(const half8*)(la + (wr * 64 + m * 16 + ln) * 32 + g * 8);
#pragma unroll
    for (int n = 0; n < 4; ++n)
      bf[n] = *(const half8*)(lb + (wc * 64 + n * 16 + ln) * 32 + g * 8);
#pragma unroll
    for (int m = 0; m < 4; ++m)
#pragma unroll
      for (int n = 0; n < 4; ++n)
        acc[m][n] = MFMA16(af[m], bf[n], acc[m][n]);
    __syncthreads();
  }

  const int b = mtile;  // 128 rows per tile == one batch
  const int colbase = ntile * 128 + wc * 64;
#pragma unroll
  for (int m = 0; m < 4; ++m) {
    const int nn0 = wr * 64 + m * 16 + g * 4;  // token row in batch (reg 0)
#pragma unroll
    for (int n = 0; n < 4; ++n) {
      const int col = colbase + n * 16 + ln;
      const int which = col >> 9;      // 0=Q 1=K 2=V (uniform per n)
      const int c = col & 511;
      const int h = c >> 6, d = c & 63;
      const float bias = (which == 0) ? bq[c] : (which == 1) ? bk[c] : bv[c];
      if (which < 2) {
        f16* dst = ((which == 0) ? qb : kb) + ((b * NH + h) * NQ + nn0) * DH + d;
#pragma unroll
        for (int r = 0; r < 4; ++r)
          dst[r * DH] = (f16)(acc[m][n][r] + bias);
      } else {
        half4 v4;
#pragma unroll
        for (int r = 0; r < 4; ++r)
          v4[r] = (f16)(acc[m][n][r] + bias);
        *(half4*)(vb + ((b * NH + h) * DH + d) * NQ + nn0) = v4;  // V^T
      }
    }
  }
}

// ---------------- kernel 2: causal attention, one block per (b,h) ----------------
__global__ __launch_bounds__(256, 2) void k_attn(
    const f16* __restrict__ qbuf, const f16* __restrict__ kbuf,
    const f16* __restrict__ vbuf, f16* __restrict__ ao) {
  __shared__ f16 kl[128 * 72];   // K [key][d], padded stride 72
  __shared__ f16 vl[64 * 136];   // V^T [d][key], padded stride 136
  __shared__ f16 pl[128 * 136];  // P [q][key], padded stride 136
  const int bh = blockIdx.x;
  const f16* Qp = qbuf + bh * (NQ * DH);
  const f16* Kp = kbuf + bh * (NQ * DH);
  const f16* Vp = vbuf + bh * (DH * NQ);
  const int tid = threadIdx.x;
  const int w = tid >> 6, lane = tid & 63;
  const int ln = lane & 15, g = lane >> 4;

  // stage K (128x64) and V^T (64x128) into padded LDS, 16B per lane per iter
#pragma unroll
  for (int i = 0; i < 4; ++i) {
    const int e = i * 2048 + tid * 8;
    *(half8*)(kl + (e >> 6) * 72 + (e & 63)) = *(const half8*)(Kp + e);
  }
#pragma unroll
  for (int i = 0; i < 4; ++i) {
    const int e = i * 2048 + tid * 8;
    *(half8*)(vl + (e >> 7) * 136 + (e & 127)) = *(const half8*)(Vp + e);
  }
  // Q fragments straight from global (L2/L3 resident)
  half8 qf[2][2];
#pragma unroll
  for (int m = 0; m < 2; ++m)
#pragma unroll
    for (int ks = 0; ks < 2; ++ks)
      qf[m][ks] = *(const half8*)(Qp + (w * 32 + m * 16 + ln) * DH + ks * 32 + g * 8);
  __syncthreads();

  // S = Q K^T  (wave w owns q-rows [w*32, w*32+32))
  f32x4 s[2][8] = {};
#pragma unroll
  for (int ks = 0; ks < 2; ++ks)
#pragma unroll
    for (int n = 0; n < 8; ++n) {
      half8 kf = *(const half8*)(kl + (n * 16 + ln) * 72 + ks * 32 + g * 8);
      s[0][n] = MFMA16(qf[0][ks], kf, s[0][n]);
      s[1][n] = MFMA16(qf[1][ks], kf, s[1][n]);
    }

  // softmax: z = s*0.125 (masked: -12500); row stats via 16-lane xor-shuffle
  float inv[2][4];
#pragma unroll
  for (int m = 0; m < 2; ++m) {
#pragma unroll
    for (int r = 0; r < 4; ++r) {
      const int q = w * 32 + m * 16 + g * 4 + r;
      float z[8];
      float rm = -1e30f;
#pragma unroll
      for (int n = 0; n < 8; ++n) {
        const int col = n * 16 + ln;
        float zz = s[m][n][r] * 0.125f + ((col > q) ? -12500.0f : 0.0f);
        z[n] = zz;
        rm = fmaxf(rm, zz);
      }
      rm = fmaxf(rm, __shfl_xor(rm, 1));
      rm = fmaxf(rm, __shfl_xor(rm, 2));
      rm = fmaxf(rm, __shfl_xor(rm, 4));
      rm = fmaxf(rm, __shfl_xor(rm, 8));
      float rs = 0.f;
#pragma unroll
      for (int n = 0; n < 8; ++n) {
        const float p = __expf(z[n] - rm);  // masked cols underflow to exact 0
        rs += p;
        pl[q * 136 + n * 16 + ln] = (f16)p;  // unnormalized P
      }
      rs += __shfl_xor(rs, 1);
      rs += __shfl_xor(rs, 2);
      rs += __shfl_xor(rs, 4);
      rs += __shfl_xor(rs, 8);
      inv[m][r] = 1.0f / rs;
    }
  }

  // O = P V   (wave-local rows only; same-wave LDS dependency, no barrier needed)
  f32x4 o[2][4] = {};
#pragma unroll
  for (int ks = 0; ks < 4; ++ks) {
    half8 pf0 = *(const half8*)(pl + (w * 32 + ln) * 136 + ks * 32 + g * 8);
    half8 pf1 = *(const half8*)(pl + (w * 32 + 16 + ln) * 136 + ks * 32 + g * 8);
#pragma unroll
    for (int n = 0; n < 4; ++n) {
      half8 vf = *(const half8*)(vl + (n * 16 + ln) * 136 + ks * 32 + g * 8);
      o[0][n] = MFMA16(pf0, vf, o[0][n]);
      o[1][n] = MFMA16(pf1, vf, o[1][n]);
    }
  }

  // store O normalized, token-major [b][q][h*64+d]
  const int b = bh >> 3, h = bh & 7;
  f16* dst = ao + (b * NQ) * CH + h * DH;
#pragma unroll
  for (int m = 0; m < 2; ++m)
#pragma unroll
    for (int n = 0; n < 4; ++n)
#pragma unroll
      for (int r = 0; r < 4; ++r) {
        const int q = w * 32 + m * 16 + g * 4 + r;
        dst[q * CH + n * 16 + ln] = (f16)(o[m][n][r] * inv[m][r]);
      }
}

// ---------------- kernel 3: output projection GEMM ----------------
__global__ __launch_bounds__(256, 2) void k_out(
    f16* __restrict__ A, f16* __restrict__ Bw,
    const float* __restrict__ bo, float* __restrict__ out) {
  __shared__ f16 la[128 * 32];
  __shared__ f16 lb[128 * 32];
  const int tid = threadIdx.x;
  const int w = tid >> 6, lane = tid & 63;
  const int ln = lane & 15, g = lane >> 4;
  const int wr = w >> 1, wc = w & 1;
  const int mtile = blockIdx.y, ntile = blockIdx.x;

  const int e0 = w * 512 + lane * 8;
  const int srow = e0 >> 5, scol = e0 & 31;
  f16* gA = A + (mtile * 128 + srow) * KD + scol;
  f16* gB = Bw + (ntile * 128 + srow) * KD + scol;
  f16* lA = la + w * 512;
  f16* lB = lb + w * 512;

  f32x4 acc[4][4] = {};

  for (int kt = 0; kt < 16; ++kt) {
    const int k0 = kt * 32;
    GLDS16(gA + k0, lA);
    GLDS16(gA + 64 * KD + k0, lA + 2048);
    GLDS16(gB + k0, lB);
    GLDS16(gB + 64 * KD + k0, lB + 2048);
    __syncthreads();
    half8 af[4], bf[4];
#pragma unroll
    for (int m = 0; m < 4; ++m)
      af[m] = *(const half8*)(la + (wr * 64 + m * 16 + ln) * 32 + g * 8);
#pragma unroll
    for (int n = 0; n < 4; ++n)
      bf[n] = *(const half8*)(lb + (wc * 64 + n * 16 + ln) * 32 + g * 8);
#pragma unroll
    for (int m = 0; m < 4; ++m)
#pragma unroll
      for (int n = 0; n < 4; ++n)
        acc[m][n] = MFMA16(af[m], bf[n], acc[m][n]);
    __syncthreads();
  }

  const int colbase = ntile * 128 + wc * 64;
#pragma unroll
  for (int m = 0; m < 4; ++m) {
    const int tok0 = mtile * 128 + wr * 64 + m * 16 + g * 4;
#pragma unroll
    for (int n = 0; n < 4; ++n) {
      const int col = colbase + n * 16 + ln;
      const float bias = bo[col];
      float* dst = out + tok0 * CH + col;
#pragma unroll
      for (int r = 0; r < 4; ++r)
        dst[r * CH] = acc[m][n][r] + bias;
    }
  }
}

extern "C" void kernel_launch(void* const* d_in, const int* in_sizes, int n_in,
                              void* d_out, int out_size, void* d_ws, size_t ws_size,
                              hipStream_t stream) {
  (void)in_sizes; (void)n_in; (void)out_size; (void)ws_size;
  const float* x  = (const float*)d_in[0];
  const float* Wq = (const float*)d_in[1];
  const float* bq = (const float*)d_in[2];
  const float* Wk = (const float*)d_in[3];
  const float* bk = (const float*)d_in[4];
  const float* Wv = (const float*)d_in[5];
  const float* bv = (const float*)d_in[6];
  const float* Wo = (const float*)d_in[7];
  const float* bo = (const float*)d_in[8];
  float* out = (float*)d_out;

  char* ws = (char*)d_ws;
  const size_t SZ = (size_t)MTOK * KD * sizeof(f16);  // 64 MB
  f16* xb = (f16*)(ws);                // x in fp16
  f16* qb = (f16*)(ws + SZ);           // Q [b][h][n][d]
  f16* kb = (f16*)(ws + 2 * SZ);       // K [b][h][n][d]
  f16* vb = (f16*)(ws + 3 * SZ);       // V^T [b][h][d][n]
  f16* wt = (f16*)(ws + 4 * SZ);       // W^T fp16, 2048x512
  f16* ao = xb;                        // attn out aliases xb (xb dead by then)

  k_cvt<<<2048, 256, 0, stream>>>(x, xb);
  k_wt<<<2048, 256, 0, stream>>>(Wq, Wk, Wv, Wo, wt);
  k_qkv<<<dim3(12, 512), 256, 0, stream>>>(xb, wt, bq, bk, bv, qb, kb, vb);
  k_attn<<<4096, 256, 0, stream>>>(qb, kb, vb, ao);
  k_out<<<dim3(4, 512), 256, 0, stream>>>(ao, wt + 1536 * KD, bo, out);
}